// Round 4
// baseline (1053.344 us; speedup 1.0000x reference)
//
#include <hip/hip_runtime.h>

typedef __bf16 bf16_t;
typedef bf16_t bf16x8 __attribute__((ext_vector_type(8)));
typedef bf16_t bf16x4 __attribute__((ext_vector_type(4)));
typedef float f32x4 __attribute__((ext_vector_type(4)));

#define S_LEN 1025
#define B_ROWS 1032    // per-batch padded rows (8*129); 16*1032 = 16512 = 129 tiles
#define M_P 16512
#define SP 1152        // padded seq stride for V^T (9*128)

// ---------------- fp32 -> bf16 convert (all 4 weight blobs, one launch) ----------------
__global__ __launch_bounds__(256) void cvt_kernel(const float* __restrict__ qkv_w,
                                                  const float* __restrict__ proj_w,
                                                  const float* __restrict__ fc1_w,
                                                  const float* __restrict__ fc2_w,
                                                  bf16_t* __restrict__ out) {
  const int i = blockIdx.x * 256 + threadIdx.x;  // vec4 index, total 3145728
  const float* src;
  int j = i;
  if (j < 786432) src = qkv_w;
  else if ((j -= 786432) < 262144) src = proj_w;
  else if ((j -= 262144) < 1048576) src = fc1_w;
  else { j -= 1048576; src = fc2_w; }
  const float4 v = ((const float4*)src)[j];
  bf16x4 o;
  o[0] = (bf16_t)v.x; o[1] = (bf16_t)v.y; o[2] = (bf16_t)v.z; o[3] = (bf16_t)v.w;
  ((bf16x4*)out)[i] = o;
}

// ---------------- LayerNorm (fp32 unpadded in -> bf16 padded out) ----------------
__global__ __launch_bounds__(256) void ln_kernel(const float* __restrict__ x,
                                                 const float* __restrict__ g,
                                                 const float* __restrict__ bta,
                                                 bf16_t* __restrict__ o) {
  const int s = blockIdx.x, bb = blockIdx.y;
  const int t = threadIdx.x;
  const float4 v = ((const float4*)(x + ((long)bb * S_LEN + s) * 1024))[t];
  float sm = v.x + v.y + v.z + v.w;
  float sq = v.x * v.x + v.y * v.y + v.z * v.z + v.w * v.w;
#pragma unroll
  for (int off = 32; off > 0; off >>= 1) {
    sm += __shfl_down(sm, off);
    sq += __shfl_down(sq, off);
  }
  __shared__ float red[16];
  const int w = t >> 6, lane = t & 63;
  if (lane == 0) { red[w] = sm; red[8 + w] = sq; }
  __syncthreads();
  if (t == 0) {
    const float ts = red[0] + red[1] + red[2] + red[3];
    const float tq = red[8] + red[9] + red[10] + red[11];
    const float mean = ts * (1.0f / 1024.0f);
    const float var = tq * (1.0f / 1024.0f) - mean * mean;
    red[0] = mean;
    red[1] = rsqrtf(var + 1e-5f);
  }
  __syncthreads();
  const float mean = red[0], rstd = red[1];
  const float4 gg = ((const float4*)g)[t];
  const float4 bb2 = ((const float4*)bta)[t];
  bf16x4 ov;
  ov[0] = (bf16_t)((v.x - mean) * rstd * gg.x + bb2.x);
  ov[1] = (bf16_t)((v.y - mean) * rstd * gg.y + bb2.y);
  ov[2] = (bf16_t)((v.z - mean) * rstd * gg.z + bb2.z);
  ov[3] = (bf16_t)((v.w - mean) * rstd * gg.w + bb2.w);
  ((bf16x4*)(o + ((long)bb * B_ROWS + s) * 1024))[t] = ov;
}

// ---------------- GEMM C = A @ W^T (+epilogue) ----------------
// A [M_P,K] bf16 row-major (batch-padded rows), W [N,K] bf16 row-major.
// 128x128 tile, BK=32, 4 waves 2x2, 4x4 MFMA 16x16x32 each.
// K-loop: 3-deep LDS ring (3 x 16KB = 48KB -> 3 blocks/CU), stage distance 2,
// counted s_waitcnt vmcnt(4) (never 0 in-loop; last K-step peeled with vmcnt(0)),
// one raw s_barrier per K-step, setprio(1) around the MFMA cluster (T4+T5).
// T2: LDS staged linearly by global_load_lds; bank-conflict-free frag reads via
// pre-swizzled GLOBAL source chunk c^=(row>>1)&3 and the same XOR on the
// ds_read address (measured: SQ_LDS_BANK_CONFLICT = 0).
// 1-D grid, XCD-swizzled: bid&7 = XCD slice of 17 m-tiles, n fastest within.
enum { EPI_QKV = 0, EPI_PROJ = 1, EPI_FC2 = 3, EPI_FC1 = 2 };

template <int EPI>
__global__ __launch_bounds__(256) void gemm_bt(const bf16_t* __restrict__ A,
                                               const bf16_t* __restrict__ W,
                                               const float* __restrict__ bias,
                                               const float* __restrict__ resid,
                                               const float* __restrict__ ls,
                                               bf16_t* __restrict__ outb,
                                               float* __restrict__ outf,
                                               bf16_t* __restrict__ vt,
                                               int N, int K, int NT) {
  const int g = blockIdx.x & 7;
  const int rr = blockIdx.x >> 3;
  const int ntile = rr % NT;
  const int mloc = rr / NT;
  const int mtile = g * 17 + mloc;
  if (mtile >= 129) return;
  const int n0 = ntile * 128;
  const int m0 = mtile * 128;

  // LDS: 3-ring of K-tiles, each {A[128][32] 8KB | B[128][32] 8KB} = 16KB.
  // Epilogue overlays C-stage (<=34304B) over ring slots 0-2.
  __shared__ __align__(16) char smem[49152];

  const int t = threadIdx.x;
  const int w = t >> 6;
  const int lane = t & 63;
  const int wm = (w >> 1) * 64;
  const int wn = (w & 1) * 64;
  const int ln = lane & 15;
  const int quad = lane >> 4;

  const f32x4 zero4 = {0.0f, 0.0f, 0.0f, 0.0f};
  f32x4 acc[4][4];
#pragma unroll
  for (int i = 0; i < 4; ++i)
#pragma unroll
    for (int j = 0; j < 4; ++j) acc[i][j] = zero4;

  // staging source: thread t instr i covers LDS dest chunk o=(i*256+t)*16
  // -> row = (i*256+t)>>2, slot = t&3; source k-chunk = slot ^ ((row>>1)&3)
  const int sr0 = t >> 2, sr1 = (t + 256) >> 2;
  const int sc0 = (t & 3) ^ ((sr0 >> 1) & 3);
  const int sc1 = (t & 3) ^ ((sr1 >> 1) & 3);
  const bf16_t* a0 = A + (long)(m0 + sr0) * K + sc0 * 8;
  const bf16_t* a1 = A + (long)(m0 + sr1) * K + sc1 * 8;
  const bf16_t* b0 = W + (long)(n0 + sr0) * K + sc0 * 8;
  const bf16_t* b1 = W + (long)(n0 + sr1) * K + sc1 * 8;

  // frag-read lane offset (bytes): row=base+ln, k-chunk quad, swizzled
  const int laneOff = ln * 64 + ((quad ^ ((ln >> 1) & 3)) << 4);

#define STAGE(KT, RING)                                                                       \
  {                                                                                           \
    char* dA_ = smem + (RING) * 16384;                                                        \
    char* dB_ = dA_ + 8192;                                                                   \
    __builtin_amdgcn_global_load_lds(                                                         \
        (const __attribute__((address_space(1))) void*)(a0 + (KT)),                           \
        (__attribute__((address_space(3))) void*)(dA_ + t * 16), 16, 0, 0);                   \
    __builtin_amdgcn_global_load_lds(                                                         \
        (const __attribute__((address_space(1))) void*)(a1 + (KT)),                           \
        (__attribute__((address_space(3))) void*)(dA_ + (t + 256) * 16), 16, 0, 0);           \
    __builtin_amdgcn_global_load_lds(                                                         \
        (const __attribute__((address_space(1))) void*)(b0 + (KT)),                           \
        (__attribute__((address_space(3))) void*)(dB_ + t * 16), 16, 0, 0);                   \
    __builtin_amdgcn_global_load_lds(                                                         \
        (const __attribute__((address_space(1))) void*)(b1 + (KT)),                           \
        (__attribute__((address_space(3))) void*)(dB_ + (t + 256) * 16), 16, 0, 0);           \
  }

  // prologue: stage tiles 0,1 -> 8 loads in flight per wave
  STAGE(0, 0)
  STAGE(32, 1)

  const int NTILES = K >> 5;
  int cur = 0;
  for (int T = 0; T < NTILES - 1; ++T) {
    // retire tile T's 4 loads (leaves tile T+1's 4 in flight); barrier makes
    // all waves' DMA writes visible. Never vmcnt(0) in this loop.
    asm volatile("s_waitcnt vmcnt(4)" ::: "memory");
    __builtin_amdgcn_s_barrier();
    __builtin_amdgcn_sched_barrier(0);

    const char* ringA = smem + cur * 16384;
    const char* ringB = ringA + 8192;
    bf16x8 af[4], bfr[4];
#pragma unroll
    for (int mt = 0; mt < 4; ++mt)
      af[mt] = *(const bf16x8*)(ringA + (wm + mt * 16) * 64 + laneOff);
#pragma unroll
    for (int nt = 0; nt < 4; ++nt)
      bfr[nt] = *(const bf16x8*)(ringB + (wn + nt * 16) * 64 + laneOff);

    // stage tile T+2 into slot (cur+2)%3 (= slot read at step T-1, safe)
    if (T + 2 < NTILES) {
      const int stg = (cur == 0) ? 2 : cur - 1;
      STAGE((T + 2) * 32, stg)
    }
    __builtin_amdgcn_sched_barrier(0);  // pin stage-issue above the MFMA cluster

    __builtin_amdgcn_s_setprio(1);
#pragma unroll
    for (int mt = 0; mt < 4; ++mt)
#pragma unroll
      for (int nt = 0; nt < 4; ++nt)
        acc[mt][nt] = __builtin_amdgcn_mfma_f32_16x16x32_bf16(af[mt], bfr[nt], acc[mt][nt], 0, 0, 0);
    __builtin_amdgcn_s_setprio(0);
    cur = (cur == 2) ? 0 : cur + 1;
  }
  // peeled last K-step: drain remaining loads fully
  {
    asm volatile("s_waitcnt vmcnt(0)" ::: "memory");
    __builtin_amdgcn_s_barrier();
    const char* ringA = smem + cur * 16384;
    const char* ringB = ringA + 8192;
    bf16x8 af[4], bfr[4];
#pragma unroll
    for (int mt = 0; mt < 4; ++mt)
      af[mt] = *(const bf16x8*)(ringA + (wm + mt * 16) * 64 + laneOff);
#pragma unroll
    for (int nt = 0; nt < 4; ++nt)
      bfr[nt] = *(const bf16x8*)(ringB + (wn + nt * 16) * 64 + laneOff);
#pragma unroll
    for (int mt = 0; mt < 4; ++mt)
#pragma unroll
      for (int nt = 0; nt < 4; ++nt)
        acc[mt][nt] = __builtin_amdgcn_mfma_f32_16x16x32_bf16(af[mt], bfr[nt], acc[mt][nt], 0, 0, 0);
  }
#undef STAGE
  __syncthreads();  // all waves done with ring before C-stage overlay

  // C/D frag layout: col = lane&15, row = quad*4+reg (m89-verified)
  if (EPI == EPI_PROJ || EPI == EPI_FC2) {
    const int b0r = m0 / B_ROWS;
    const int s0 = m0 - b0r * B_ROWS;
#pragma unroll
    for (int nt = 0; nt < 4; ++nt) {
      const int n = n0 + wn + nt * 16 + ln;
      const float bn = bias[n];
      const float lsn = ls[n];
#pragma unroll
      for (int mt = 0; mt < 4; ++mt) {
#pragma unroll
        for (int r = 0; r < 4; ++r) {
          const int d = wm + mt * 16 + quad * 4 + r;
          int s = s0 + d, b = b0r;
          if (s >= B_ROWS) { s -= B_ROWS; ++b; }
          if (s < S_LEN) {
            const long idx = ((long)b * S_LEN + s) * 1024 + n;
            outf[idx] = resid[idx] + lsn * (acc[mt][nt][r] + bn);
          }
        }
      }
    }
    return;
  }

  if (EPI == EPI_QKV && n0 >= 2048) {
    // V -> transposed C-stage [n_local][m_local], stride 134, then vector store along s
    bf16_t* C = (bf16_t*)smem;
#pragma unroll
    for (int nt = 0; nt < 4; ++nt) {
      const int nl = wn + nt * 16 + ln;
      const float bn = bias[n0 + nl];
#pragma unroll
      for (int mt = 0; mt < 4; ++mt)
#pragma unroll
        for (int r = 0; r < 4; ++r)
          C[nl * 134 + (wm + mt * 16 + quad * 4 + r)] = (bf16_t)(acc[mt][nt][r] + bn);
    }
    __syncthreads();
    const int b0r = m0 / B_ROWS;
    const int s0 = m0 - b0r * B_ROWS;
#pragma unroll
    for (int p = 0; p < 8; ++p) {
      const int nl = p * 16 + (t >> 4);
      const int sc = (t & 15) * 8;
      const int n = n0 + nl;
      const int h = (n >> 6) - 32, d = n & 63;
      int s = s0 + sc, b = b0r;
      if (s >= B_ROWS) { s -= B_ROWS; ++b; }
      *(bf16x8*)&vt[(((long)b * 16 + h) * 64 + d) * (long)SP + s] =
          *(const bf16x8*)&C[nl * 134 + sc];
    }
    return;
  }

  // QKV-qk / FC1: C-stage [m_local][n_local], stride 132, then row-contiguous b128 stores
  {
    bf16_t* C = (bf16_t*)smem;
#pragma unroll
    for (int nt = 0; nt < 4; ++nt) {
      const int nl = wn + nt * 16 + ln;
      const float bn = bias[n0 + nl];
#pragma unroll
      for (int mt = 0; mt < 4; ++mt)
#pragma unroll
        for (int r = 0; r < 4; ++r) {
          float c = acc[mt][nt][r] + bn;
          if (EPI == EPI_FC1) c = c / (1.0f + __expf(-1.702f * c));  // sigmoid-GELU
          C[(wm + mt * 16 + quad * 4 + r) * 132 + nl] = (bf16_t)c;
        }
    }
    __syncthreads();
    const long stride = (EPI == EPI_QKV) ? 2048 : N;
#pragma unroll
    for (int p = 0; p < 8; ++p) {
      const int row = p * 16 + (t >> 4);
      const int sc = (t & 15) * 8;
      *(bf16x8*)&outb[(long)(m0 + row) * stride + n0 + sc] = *(const bf16x8*)&C[row * 132 + sc];
    }
  }
}

// ---------------- Flash attention, 128-key tiles, no-max exp2 softmax ----------------
// 1-D grid 4352 = 8 XCD-groups x (32 bh x 17 qtiles); all qtiles of a bh share an XCD.
// LDS: ldsK[128][72] (18432B, overlaid by ldsP[4][16][136] after scores) + ldsV[64][136]
// = 35840B -> 4 blocks/CU.
// R4: both MFMAs operand-SWAPPED. scores = mfma(kf,qf) -> C[key_local][q=ln]:
// registers hold 4 consecutive keys at fixed q -> P[q][key] written as packed
// bf16x4 (8 b64 writes/tile, conflict-free) instead of 32 scalar b16 (which
// were the 2.26e7 bank conflicts: quad*4*272 = {0,64,0,64} mod 128).
// PV = mfma(vf,pf) -> O^T (col=q=ln): pf/vf reads unchanged; l is per-lane at
// q=ln (2 shfl_xor); output packed bf16x4 along d.
#define SCL 0.18033688f   // 0.125 * log2(e)

__global__ __launch_bounds__(256) void attn_kernel(const bf16_t* __restrict__ qk,
                                                   const bf16_t* __restrict__ vt,
                                                   bf16_t* __restrict__ out) {
  const int g = blockIdx.x & 7;
  const int idx = blockIdx.x >> 3;        // 0..543
  const int bh = g * 32 + idx / 17;
  const int q0 = (idx % 17) * 64;
  const int b = bh >> 4, h = bh & 15;
  const int t = threadIdx.x;
  const int wv = t >> 6, lane = t & 63;
  const int ln = lane & 15, quad = lane >> 4;

  __shared__ __align__(16) char smem[35840];
  bf16_t* ldsK = (bf16_t*)smem;             // [128][72]
  bf16_t* ldsP = (bf16_t*)smem;             // [4][16][136] overlay
  bf16_t* ldsV = (bf16_t*)(smem + 18432);   // [64][136]

  const long rowbase = (long)b * B_ROWS;

  int qrow = q0 + wv * 16 + ln;
  if (qrow > S_LEN - 1) qrow = S_LEN - 1;
  const bf16_t* qp = qk + (rowbase + qrow) * 2048 + h * 64;
  const bf16x8 qf0 = *(const bf16x8*)(qp + quad * 8);
  const bf16x8 qf1 = *(const bf16x8*)(qp + 32 + quad * 8);

  const bf16_t* vbase = vt + (long)bh * 64 * SP;

  const f32x4 zero4 = {0.0f, 0.0f, 0.0f, 0.0f};
  f32x4 oacc[4];
  float l_sum = 0.0f;
#pragma unroll
  for (int i = 0; i < 4; ++i) oacc[i] = zero4;

  for (int k0 = 0; k0 < 1152; k0 += 128) {
    __syncthreads();
#pragma unroll
    for (int i = 0; i < 4; ++i) {
      const int slot = t + i * 256;
      const int key = slot >> 3, ch = (slot & 7) * 8;
      int krow = k0 + key;
      if (krow > S_LEN - 1) krow = S_LEN - 1;
      *(bf16x8*)&ldsK[key * 72 + ch] =
          *(const bf16x8*)(qk + (rowbase + krow) * 2048 + 1024 + h * 64 + ch);
    }
#pragma unroll
    for (int i = 0; i < 4; ++i) {
      const int slot = t + i * 256;
      const int dim = slot >> 4, kc = (slot & 15) * 8;
      *(bf16x8*)&ldsV[dim * 136 + kc] = *(const bf16x8*)(vbase + (long)dim * SP + k0 + kc);
    }
    __syncthreads();

    // scores SWAPPED: s = K·Q^T -> row = key_local (quad*4+r), col = q (ln)
    f32x4 s[8];
#pragma unroll
    for (int nt = 0; nt < 8; ++nt) {
      const bf16x8 kf0 = *(const bf16x8*)&ldsK[(nt * 16 + ln) * 72 + quad * 8];
      const bf16x8 kf1 = *(const bf16x8*)&ldsK[(nt * 16 + ln) * 72 + 32 + quad * 8];
      f32x4 a = zero4;
      a = __builtin_amdgcn_mfma_f32_16x16x32_bf16(kf0, qf0, a, 0, 0, 0);
      a = __builtin_amdgcn_mfma_f32_16x16x32_bf16(kf1, qf1, a, 0, 0, 0);
#pragma unroll
      for (int r = 0; r < 4; ++r) s[nt][r] = a[r] * SCL;
    }
    if (k0 + 128 > S_LEN) {  // tail tile only: mask invalid keys -> p = exp2(-1e30) = 0
#pragma unroll
      for (int nt = 0; nt < 8; ++nt) {
#pragma unroll
        for (int r = 0; r < 4; ++r) {
          const bool valid = (k0 + nt * 16 + quad * 4 + r) < S_LEN;
          s[nt][r] = valid ? s[nt][r] : -1e30f;
        }
      }
    }
    __syncthreads();  // all waves done reading K frags; ldsP may overwrite ldsK

    // p = exp2(s); lane owns q=ln, keys nt*16+quad*4+{0..3} -> packed b64 writes
    bf16_t* P = ldsP + wv * 2176;
#pragma unroll
    for (int nt = 0; nt < 8; ++nt) {
      bf16x4 pv;
#pragma unroll
      for (int r = 0; r < 4; ++r) {
        const float p = exp2f(s[nt][r]);
        l_sum += p;
        pv[r] = (bf16_t)p;
      }
      *(bf16x4*)&P[ln * 136 + nt * 16 + quad * 4] = pv;
    }

    // PV SWAPPED: oacc = V^T·P^T = O^T (row = d_local, col = q = ln).
    // pf/vf reads identical to pre-swap; own wave's P region, no barrier.
#pragma unroll
    for (int ko = 0; ko < 4; ++ko) {
      const bf16x8 pf = *(const bf16x8*)&P[ln * 136 + ko * 32 + quad * 8];
#pragma unroll
      for (int dt = 0; dt < 4; ++dt) {
        const bf16x8 vf = *(const bf16x8*)&ldsV[(dt * 16 + ln) * 136 + ko * 32 + quad * 8];
        oacc[dt] = __builtin_amdgcn_mfma_f32_16x16x32_bf16(vf, pf, oacc[dt], 0, 0, 0);
      }
    }
  }

  // l[q=ln]: partials live across the 4 quads -> 2 shfl_xor
  l_sum += __shfl_xor(l_sum, 16);
  l_sum += __shfl_xor(l_sum, 32);

  const int q = q0 + wv * 16 + ln;
  if (q < S_LEN) {
    const float inv = 1.0f / l_sum;
#pragma unroll
    for (int dt = 0; dt < 4; ++dt) {
      bf16x4 ov;
#pragma unroll
      for (int r = 0; r < 4; ++r) ov[r] = (bf16_t)(oacc[dt][r] * inv);
      *(bf16x4*)&out[(rowbase + q) * 1024 + h * 64 + dt * 16 + quad * 4] = ov;
    }
  }
}

// ---------------- launch ----------------
extern "C" void kernel_launch(void* const* d_in, const int* in_sizes, int n_in,
                              void* d_out, int out_size, void* d_ws, size_t ws_size,
                              hipStream_t stream) {
  (void)in_sizes; (void)n_in; (void)out_size; (void)ws_size;
  const float* hidden = (const float*)d_in[0];
  const float* n1g = (const float*)d_in[1];
  const float* n1b = (const float*)d_in[2];
  const float* qkv_w = (const float*)d_in[3];
  const float* qkv_b = (const float*)d_in[4];
  const float* proj_w = (const float*)d_in[5];
  const float* proj_b = (const float*)d_in[6];
  const float* ls1 = (const float*)d_in[7];
  const float* n2g = (const float*)d_in[8];
  const float* n2b = (const float*)d_in[9];
  const float* fc1_w = (const float*)d_in[10];
  const float* fc1_b = (const float*)d_in[11];
  const float* fc2_w = (const float*)d_in[12];
  const float* fc2_b = (const float*)d_in[13];
  const float* ls2 = (const float*)d_in[14];
  float* out = (float*)d_out;

  // workspace layout (bytes):
  //  R1:     16512*1024*2 = 33,816,576      (xnorm -> attn_out -> ynorm, padded rows)
  //  SHARED: 135,266,304   {qk 67,633,152 + vt 37,748,736}  OR  gelu 16512*4096*2
  //  W:      bf16 weights 25,165,824 (qkv|proj|fc1|fc2 contiguous)
  char* ws = (char*)d_ws;
  bf16_t* R1 = (bf16_t*)ws;
  char* shared = ws + 33816576L;
  bf16_t* qkbuf = (bf16_t*)shared;                  // [16512, 2048]
  bf16_t* vtbuf = (bf16_t*)(shared + 67633152L);    // [256, 64, SP]
  bf16_t* gelu = (bf16_t*)shared;                   // [16512, 4096]
  bf16_t* wqkv = (bf16_t*)(ws + 33816576L + 135266304L);
  bf16_t* wproj = wqkv + 3145728;
  bf16_t* wfc1 = wproj + 1048576;
  bf16_t* wfc2 = wfc1 + 4194304;

  cvt_kernel<<<12288, 256, 0, stream>>>(qkv_w, proj_w, fc1_w, fc2_w, wqkv);

  // LN1: hidden -> R1 (bf16, padded rows)
  ln_kernel<<<dim3(S_LEN, 16), 256, 0, stream>>>(hidden, n1g, n1b, R1);

  // QKV: Q,K -> qkbuf [M_P,2048]; V -> vtbuf transposed
  gemm_bt<EPI_QKV><<<136 * 24, 256, 0, stream>>>(R1, wqkv, qkv_b, nullptr, nullptr,
                                                 qkbuf, nullptr, vtbuf, 3072, 1024, 24);

  // attention: qkbuf/vtbuf -> R1 [M_P,1024]
  attn_kernel<<<4352, 256, 0, stream>>>(qkbuf, vtbuf, R1);

  // proj + residual: out = hidden + ls1*(R1 @ wproj^T + b)
  gemm_bt<EPI_PROJ><<<136 * 8, 256, 0, stream>>>(R1, wproj, proj_b, hidden, ls1,
                                                 nullptr, out, nullptr, 1024, 1024, 8);

  // LN2: out -> R1
  ln_kernel<<<dim3(S_LEN, 16), 256, 0, stream>>>(out, n2g, n2b, R1);

  // FC1 + GELU: R1 @ wfc1^T + b -> gelu [M_P,4096]
  gemm_bt<EPI_FC1><<<136 * 32, 256, 0, stream>>>(R1, wfc1, fc1_b, nullptr, nullptr,
                                                 gelu, nullptr, nullptr, 4096, 1024, 32);

  // FC2 + residual: out += ls2*(gelu @ wfc2^T + b)
  gemm_bt<EPI_FC2><<<136 * 8, 256, 0, stream>>>(gelu, wfc2, fc2_b, out, ls2,
                                                nullptr, out, nullptr, 1024, 4096, 8);
}

// Round 5
// 967.437 us; speedup vs baseline: 1.0888x; 1.0888x over previous
//
#include <hip/hip_runtime.h>

typedef __bf16 bf16_t;
typedef bf16_t bf16x8 __attribute__((ext_vector_type(8)));
typedef bf16_t bf16x4 __attribute__((ext_vector_type(4)));
typedef float f32x4 __attribute__((ext_vector_type(4)));

#define S_LEN 1025
#define B_ROWS 1032    // per-batch padded rows (8*129); 16*1032 = 16512 = 129 tiles
#define M_P 16512
#define SP 1152        // padded seq stride for V^T (9*128)
#define SCL 0.18033688f   // 0.125 * log2(e) — folded into Q at the QKV epilogue

// ---------------- fp32 -> bf16 convert (all 4 weight blobs, one launch) ----------------
__global__ __launch_bounds__(256) void cvt_kernel(const float* __restrict__ qkv_w,
                                                  const float* __restrict__ proj_w,
                                                  const float* __restrict__ fc1_w,
                                                  const float* __restrict__ fc2_w,
                                                  bf16_t* __restrict__ out) {
  const int i = blockIdx.x * 256 + threadIdx.x;  // vec4 index, total 3145728
  const float* src;
  int j = i;
  if (j < 786432) src = qkv_w;
  else if ((j -= 786432) < 262144) src = proj_w;
  else if ((j -= 262144) < 1048576) src = fc1_w;
  else { j -= 1048576; src = fc2_w; }
  const float4 v = ((const float4*)src)[j];
  bf16x4 o;
  o[0] = (bf16_t)v.x; o[1] = (bf16_t)v.y; o[2] = (bf16_t)v.z; o[3] = (bf16_t)v.w;
  ((bf16x4*)out)[i] = o;
}

// ---------------- LayerNorm (fp32 unpadded in -> bf16 padded out) ----------------
__global__ __launch_bounds__(256) void ln_kernel(const float* __restrict__ x,
                                                 const float* __restrict__ g,
                                                 const float* __restrict__ bta,
                                                 bf16_t* __restrict__ o) {
  const int s = blockIdx.x, bb = blockIdx.y;
  const int t = threadIdx.x;
  const float4 v = ((const float4*)(x + ((long)bb * S_LEN + s) * 1024))[t];
  float sm = v.x + v.y + v.z + v.w;
  float sq = v.x * v.x + v.y * v.y + v.z * v.z + v.w * v.w;
#pragma unroll
  for (int off = 32; off > 0; off >>= 1) {
    sm += __shfl_down(sm, off);
    sq += __shfl_down(sq, off);
  }
  __shared__ float red[16];
  const int w = t >> 6, lane = t & 63;
  if (lane == 0) { red[w] = sm; red[8 + w] = sq; }
  __syncthreads();
  if (t == 0) {
    const float ts = red[0] + red[1] + red[2] + red[3];
    const float tq = red[8] + red[9] + red[10] + red[11];
    const float mean = ts * (1.0f / 1024.0f);
    const float var = tq * (1.0f / 1024.0f) - mean * mean;
    red[0] = mean;
    red[1] = rsqrtf(var + 1e-5f);
  }
  __syncthreads();
  const float mean = red[0], rstd = red[1];
  const float4 gg = ((const float4*)g)[t];
  const float4 bb2 = ((const float4*)bta)[t];
  bf16x4 ov;
  ov[0] = (bf16_t)((v.x - mean) * rstd * gg.x + bb2.x);
  ov[1] = (bf16_t)((v.y - mean) * rstd * gg.y + bb2.y);
  ov[2] = (bf16_t)((v.z - mean) * rstd * gg.z + bb2.z);
  ov[3] = (bf16_t)((v.w - mean) * rstd * gg.w + bb2.w);
  ((bf16x4*)(o + ((long)bb * B_ROWS + s) * 1024))[t] = ov;
}

// ---------------- GEMM C = A @ W^T (+epilogue) ----------------
// A [M_P,K] bf16 row-major (batch-padded rows), W [N,K] bf16 row-major.
// 128x128 tile, BK=32, 4 waves 2x2, 4x4 MFMA 16x16x32 each.
// K-loop: 3-deep LDS ring (3 x 16KB = 48KB -> 3 blocks/CU), stage distance 2,
// counted s_waitcnt vmcnt(4) (never 0 in-loop; last K-step peeled with vmcnt(0)),
// one raw s_barrier per K-step, setprio(1) around the MFMA cluster (T4+T5).
// T2: LDS staged linearly by global_load_lds; bank-conflict-free frag reads via
// pre-swizzled GLOBAL source chunk c^=(row>>1)&3 and the same XOR on the
// ds_read address (measured: SQ_LDS_BANK_CONFLICT = 0).
// 1-D grid, XCD-swizzled: bid&7 = XCD slice of 17 m-tiles, n fastest within.
enum { EPI_QKV = 0, EPI_PROJ = 1, EPI_FC2 = 3, EPI_FC1 = 2 };

template <int EPI>
__global__ __launch_bounds__(256) void gemm_bt(const bf16_t* __restrict__ A,
                                               const bf16_t* __restrict__ W,
                                               const float* __restrict__ bias,
                                               const float* __restrict__ resid,
                                               const float* __restrict__ ls,
                                               bf16_t* __restrict__ outb,
                                               float* __restrict__ outf,
                                               bf16_t* __restrict__ vt,
                                               int N, int K, int NT) {
  const int g = blockIdx.x & 7;
  const int rr = blockIdx.x >> 3;
  const int ntile = rr % NT;
  const int mloc = rr / NT;
  const int mtile = g * 17 + mloc;
  if (mtile >= 129) return;
  const int n0 = ntile * 128;
  const int m0 = mtile * 128;

  // LDS: 3-ring of K-tiles, each {A[128][32] 8KB | B[128][32] 8KB} = 16KB.
  // Epilogue overlays C-stage (<=34304B) over ring slots 0-2.
  __shared__ __align__(16) char smem[49152];

  const int t = threadIdx.x;
  const int w = t >> 6;
  const int lane = t & 63;
  const int wm = (w >> 1) * 64;
  const int wn = (w & 1) * 64;
  const int ln = lane & 15;
  const int quad = lane >> 4;

  const f32x4 zero4 = {0.0f, 0.0f, 0.0f, 0.0f};
  f32x4 acc[4][4];
#pragma unroll
  for (int i = 0; i < 4; ++i)
#pragma unroll
    for (int j = 0; j < 4; ++j) acc[i][j] = zero4;

  // staging source: thread t instr i covers LDS dest chunk o=(i*256+t)*16
  // -> row = (i*256+t)>>2, slot = t&3; source k-chunk = slot ^ ((row>>1)&3)
  const int sr0 = t >> 2, sr1 = (t + 256) >> 2;
  const int sc0 = (t & 3) ^ ((sr0 >> 1) & 3);
  const int sc1 = (t & 3) ^ ((sr1 >> 1) & 3);
  const bf16_t* a0 = A + (long)(m0 + sr0) * K + sc0 * 8;
  const bf16_t* a1 = A + (long)(m0 + sr1) * K + sc1 * 8;
  const bf16_t* b0 = W + (long)(n0 + sr0) * K + sc0 * 8;
  const bf16_t* b1 = W + (long)(n0 + sr1) * K + sc1 * 8;

  // frag-read lane offset (bytes): row=base+ln, k-chunk quad, swizzled
  const int laneOff = ln * 64 + ((quad ^ ((ln >> 1) & 3)) << 4);

#define STAGE(KT, RING)                                                                       \
  {                                                                                           \
    char* dA_ = smem + (RING) * 16384;                                                        \
    char* dB_ = dA_ + 8192;                                                                   \
    __builtin_amdgcn_global_load_lds(                                                         \
        (const __attribute__((address_space(1))) void*)(a0 + (KT)),                           \
        (__attribute__((address_space(3))) void*)(dA_ + t * 16), 16, 0, 0);                   \
    __builtin_amdgcn_global_load_lds(                                                         \
        (const __attribute__((address_space(1))) void*)(a1 + (KT)),                           \
        (__attribute__((address_space(3))) void*)(dA_ + (t + 256) * 16), 16, 0, 0);           \
    __builtin_amdgcn_global_load_lds(                                                         \
        (const __attribute__((address_space(1))) void*)(b0 + (KT)),                           \
        (__attribute__((address_space(3))) void*)(dB_ + t * 16), 16, 0, 0);                   \
    __builtin_amdgcn_global_load_lds(                                                         \
        (const __attribute__((address_space(1))) void*)(b1 + (KT)),                           \
        (__attribute__((address_space(3))) void*)(dB_ + (t + 256) * 16), 16, 0, 0);           \
  }

  // prologue: stage tiles 0,1 -> 8 loads in flight per wave
  STAGE(0, 0)
  STAGE(32, 1)

  const int NTILES = K >> 5;
  int cur = 0;
  for (int T = 0; T < NTILES - 1; ++T) {
    // retire tile T's 4 loads (leaves tile T+1's 4 in flight); barrier makes
    // all waves' DMA writes visible. Never vmcnt(0) in this loop.
    asm volatile("s_waitcnt vmcnt(4)" ::: "memory");
    __builtin_amdgcn_s_barrier();
    __builtin_amdgcn_sched_barrier(0);

    const char* ringA = smem + cur * 16384;
    const char* ringB = ringA + 8192;
    bf16x8 af[4], bfr[4];
#pragma unroll
    for (int mt = 0; mt < 4; ++mt)
      af[mt] = *(const bf16x8*)(ringA + (wm + mt * 16) * 64 + laneOff);
#pragma unroll
    for (int nt = 0; nt < 4; ++nt)
      bfr[nt] = *(const bf16x8*)(ringB + (wn + nt * 16) * 64 + laneOff);

    // stage tile T+2 into slot (cur+2)%3 (= slot read at step T-1, safe)
    if (T + 2 < NTILES) {
      const int stg = (cur == 0) ? 2 : cur - 1;
      STAGE((T + 2) * 32, stg)
    }
    __builtin_amdgcn_sched_barrier(0);  // pin stage-issue above the MFMA cluster

    __builtin_amdgcn_s_setprio(1);
#pragma unroll
    for (int mt = 0; mt < 4; ++mt)
#pragma unroll
      for (int nt = 0; nt < 4; ++nt)
        acc[mt][nt] = __builtin_amdgcn_mfma_f32_16x16x32_bf16(af[mt], bfr[nt], acc[mt][nt], 0, 0, 0);
    __builtin_amdgcn_s_setprio(0);
    cur = (cur == 2) ? 0 : cur + 1;
  }
  // peeled last K-step: drain remaining loads fully
  {
    asm volatile("s_waitcnt vmcnt(0)" ::: "memory");
    __builtin_amdgcn_s_barrier();
    const char* ringA = smem + cur * 16384;
    const char* ringB = ringA + 8192;
    bf16x8 af[4], bfr[4];
#pragma unroll
    for (int mt = 0; mt < 4; ++mt)
      af[mt] = *(const bf16x8*)(ringA + (wm + mt * 16) * 64 + laneOff);
#pragma unroll
    for (int nt = 0; nt < 4; ++nt)
      bfr[nt] = *(const bf16x8*)(ringB + (wn + nt * 16) * 64 + laneOff);
#pragma unroll
    for (int mt = 0; mt < 4; ++mt)
#pragma unroll
      for (int nt = 0; nt < 4; ++nt)
        acc[mt][nt] = __builtin_amdgcn_mfma_f32_16x16x32_bf16(af[mt], bfr[nt], acc[mt][nt], 0, 0, 0);
  }
#undef STAGE
  __syncthreads();  // all waves done with ring before C-stage overlay

  // C/D frag layout: col = lane&15, row = quad*4+reg (m89-verified)
  if (EPI == EPI_PROJ || EPI == EPI_FC2) {
    const int b0r = m0 / B_ROWS;
    const int s0 = m0 - b0r * B_ROWS;
#pragma unroll
    for (int nt = 0; nt < 4; ++nt) {
      const int n = n0 + wn + nt * 16 + ln;
      const float bn = bias[n];
      const float lsn = ls[n];
#pragma unroll
      for (int mt = 0; mt < 4; ++mt) {
#pragma unroll
        for (int r = 0; r < 4; ++r) {
          const int d = wm + mt * 16 + quad * 4 + r;
          int s = s0 + d, b = b0r;
          if (s >= B_ROWS) { s -= B_ROWS; ++b; }
          if (s < S_LEN) {
            const long idx = ((long)b * S_LEN + s) * 1024 + n;
            outf[idx] = resid[idx] + lsn * (acc[mt][nt][r] + bn);
          }
        }
      }
    }
    return;
  }

  if (EPI == EPI_QKV && n0 >= 2048) {
    // V -> transposed C-stage [n_local][m_local], stride 134, then vector store along s
    bf16_t* C = (bf16_t*)smem;
#pragma unroll
    for (int nt = 0; nt < 4; ++nt) {
      const int nl = wn + nt * 16 + ln;
      const float bn = bias[n0 + nl];
#pragma unroll
      for (int mt = 0; mt < 4; ++mt)
#pragma unroll
        for (int r = 0; r < 4; ++r)
          C[nl * 134 + (wm + mt * 16 + quad * 4 + r)] = (bf16_t)(acc[mt][nt][r] + bn);
    }
    __syncthreads();
    const int b0r = m0 / B_ROWS;
    const int s0 = m0 - b0r * B_ROWS;
#pragma unroll
    for (int p = 0; p < 8; ++p) {
      const int nl = p * 16 + (t >> 4);
      const int sc = (t & 15) * 8;
      const int n = n0 + nl;
      const int h = (n >> 6) - 32, d = n & 63;
      int s = s0 + sc, b = b0r;
      if (s >= B_ROWS) { s -= B_ROWS; ++b; }
      *(bf16x8*)&vt[(((long)b * 16 + h) * 64 + d) * (long)SP + s] =
          *(const bf16x8*)&C[nl * 134 + sc];
    }
    return;
  }

  // QKV-qk / FC1: C-stage [m_local][n_local], stride 132, then row-contiguous b128 stores
  // Q columns (EPI_QKV, n0<1024) are pre-scaled by SCL so attn skips the per-score mul.
  {
    bf16_t* C = (bf16_t*)smem;
#pragma unroll
    for (int nt = 0; nt < 4; ++nt) {
      const int nl = wn + nt * 16 + ln;
      const float bn = bias[n0 + nl];
#pragma unroll
      for (int mt = 0; mt < 4; ++mt)
#pragma unroll
        for (int r = 0; r < 4; ++r) {
          float c = acc[mt][nt][r] + bn;
          if (EPI == EPI_QKV) {
            if (n0 < 1024) c *= SCL;   // uniform branch: Q pre-scale
          }
          if (EPI == EPI_FC1) c = c / (1.0f + __expf(-1.702f * c));  // sigmoid-GELU
          C[(wm + mt * 16 + quad * 4 + r) * 132 + nl] = (bf16_t)c;
        }
    }
    __syncthreads();
    const long stride = (EPI == EPI_QKV) ? 2048 : N;
#pragma unroll
    for (int p = 0; p < 8; ++p) {
      const int row = p * 16 + (t >> 4);
      const int sc = (t & 15) * 8;
      *(bf16x8*)&outb[(long)(m0 + row) * stride + n0 + sc] = *(const bf16x8*)&C[row * 132 + sc];
    }
  }
}

// ---------------- Flash attention, 8 full 128-key tiles + analytic last key ----------------
// 1-D grid 4352 = 8 XCD-groups x (32 bh x 17 qtiles); all qtiles of a bh share an XCD.
// LDS: ldsK[128][72] (18432B, overlaid by ldsP[4][16][136] after scores) + ldsV[64][136]
// = 35840B -> 4 blocks/CU.
// R5: main loop covers keys 0..1023 exactly (no clamp, no mask); the single
// remaining key s=1024 is appended analytically via a VALU dot-product with the
// register-resident Q-frags (removes the 9th tile that computed 128 columns to
// use 1). Q arrives pre-scaled by SCL (QKV epilogue), removing 32 muls/tile.
__global__ __launch_bounds__(256) void attn_kernel(const bf16_t* __restrict__ qk,
                                                   const bf16_t* __restrict__ vt,
                                                   bf16_t* __restrict__ out) {
  const int g = blockIdx.x & 7;
  const int idx = blockIdx.x >> 3;        // 0..543
  const int bh = g * 32 + idx / 17;
  const int q0 = (idx % 17) * 64;
  const int b = bh >> 4, h = bh & 15;
  const int t = threadIdx.x;
  const int wv = t >> 6, lane = t & 63;
  const int ln = lane & 15, quad = lane >> 4;

  __shared__ __align__(16) char smem[35840];
  bf16_t* ldsK = (bf16_t*)smem;             // [128][72]
  bf16_t* ldsP = (bf16_t*)smem;             // [4][16][136] overlay
  bf16_t* ldsV = (bf16_t*)(smem + 18432);   // [64][136]

  const long rowbase = (long)b * B_ROWS;

  int qrow = q0 + wv * 16 + ln;
  if (qrow > S_LEN - 1) qrow = S_LEN - 1;
  const bf16_t* qp = qk + (rowbase + qrow) * 2048 + h * 64;
  const bf16x8 qf0 = *(const bf16x8*)(qp + quad * 8);
  const bf16x8 qf1 = *(const bf16x8*)(qp + 32 + quad * 8);

  const bf16_t* vbase = vt + (long)bh * 64 * SP;

  const f32x4 zero4 = {0.0f, 0.0f, 0.0f, 0.0f};
  f32x4 oacc[4];
  float l_part[4] = {0.0f, 0.0f, 0.0f, 0.0f};
#pragma unroll
  for (int i = 0; i < 4; ++i) oacc[i] = zero4;

  for (int k0 = 0; k0 < 1024; k0 += 128) {   // 8 full tiles, keys 0..1023 all valid
    __syncthreads();
#pragma unroll
    for (int i = 0; i < 4; ++i) {
      const int slot = t + i * 256;
      const int key = slot >> 3, ch = (slot & 7) * 8;
      *(bf16x8*)&ldsK[key * 72 + ch] =
          *(const bf16x8*)(qk + (rowbase + k0 + key) * 2048 + 1024 + h * 64 + ch);
    }
#pragma unroll
    for (int i = 0; i < 4; ++i) {
      const int slot = t + i * 256;
      const int dim = slot >> 4, kc = (slot & 15) * 8;
      *(bf16x8*)&ldsV[dim * 136 + kc] = *(const bf16x8*)(vbase + (long)dim * SP + k0 + kc);
    }
    __syncthreads();

    // scores: s = Q·K^T (Q pre-scaled; exp2-ready)
    f32x4 s[8];
    __builtin_amdgcn_s_setprio(1);
#pragma unroll
    for (int nt = 0; nt < 8; ++nt) {
      const bf16x8 kf0 = *(const bf16x8*)&ldsK[(nt * 16 + ln) * 72 + quad * 8];
      const bf16x8 kf1 = *(const bf16x8*)&ldsK[(nt * 16 + ln) * 72 + 32 + quad * 8];
      f32x4 a = zero4;
      a = __builtin_amdgcn_mfma_f32_16x16x32_bf16(qf0, kf0, a, 0, 0, 0);
      a = __builtin_amdgcn_mfma_f32_16x16x32_bf16(qf1, kf1, a, 0, 0, 0);
      s[nt] = a;
    }
    __builtin_amdgcn_s_setprio(0);
    __syncthreads();  // all waves done reading K frags; ldsP may overwrite ldsK

    // p = exp2(s), per-lane partial row-sums (reduced once at the end)
    bf16_t* P = ldsP + wv * 2176;
#pragma unroll
    for (int nt = 0; nt < 8; ++nt)
#pragma unroll
      for (int r = 0; r < 4; ++r) {
        const float p = exp2f(s[nt][r]);
        l_part[r] += p;
        P[(quad * 4 + r) * 136 + nt * 16 + ln] = (bf16_t)p;
      }

    // PV: A = P[q][key] (own wave's region, no barrier needed), B = V^T rows
    __builtin_amdgcn_s_setprio(1);
#pragma unroll
    for (int ko = 0; ko < 4; ++ko) {
      const bf16x8 pf = *(const bf16x8*)&P[ln * 136 + ko * 32 + quad * 8];
#pragma unroll
      for (int dt = 0; dt < 4; ++dt) {
        const bf16x8 vf = *(const bf16x8*)&ldsV[(dt * 16 + ln) * 136 + ko * 32 + quad * 8];
        oacc[dt] = __builtin_amdgcn_mfma_f32_16x16x32_bf16(pf, vf, oacc[dt], 0, 0, 0);
      }
    }
    __builtin_amdgcn_s_setprio(0);
  }

  // l reduction across the 16 lanes of each quad-row group (keys 0..1023)
#pragma unroll
  for (int off = 1; off < 16; off <<= 1)
#pragma unroll
    for (int r = 0; r < 4; ++r) l_part[r] += __shfl_xor(l_part[r], off);

  // ---- analytic last key (s = 1024) ----
  // per-lane dot: Q[q=wv*16+ln] · K[1024] over this quad's 16 dims, then quad-reduce
  {
    const bf16_t* kp = qk + (rowbase + 1024) * 2048 + 1024 + h * 64;
    const bf16x8 kl0 = *(const bf16x8*)(kp + quad * 8);
    const bf16x8 kl1 = *(const bf16x8*)(kp + 32 + quad * 8);
    float sl = 0.0f;
#pragma unroll
    for (int j = 0; j < 8; ++j)
      sl += (float)qf0[j] * (float)kl0[j] + (float)qf1[j] * (float)kl1[j];
    sl += __shfl_xor(sl, 16);
    sl += __shfl_xor(sl, 32);   // now sl = s(q=wv*16+ln) on every quad

    float p_last[4];
#pragma unroll
    for (int r = 0; r < 4; ++r)
      p_last[r] = exp2f(__shfl(sl, quad * 4 + r));   // re-index to C-layout rows

#pragma unroll
    for (int dt = 0; dt < 4; ++dt) {
      const float vv = (float)vt[((long)bh * 64 + dt * 16 + ln) * SP + 1024];
#pragma unroll
      for (int r = 0; r < 4; ++r) oacc[dt][r] += p_last[r] * vv;
    }
#pragma unroll
    for (int r = 0; r < 4; ++r) l_part[r] += p_last[r];
  }

#pragma unroll
  for (int r = 0; r < 4; ++r) {
    const int q = q0 + wv * 16 + quad * 4 + r;
    if (q < S_LEN) {
      const float inv = 1.0f / l_part[r];
#pragma unroll
      for (int dt = 0; dt < 4; ++dt)
        out[(rowbase + q) * 1024 + h * 64 + dt * 16 + ln] = (bf16_t)(oacc[dt][r] * inv);
    }
  }
}

// ---------------- launch ----------------
extern "C" void kernel_launch(void* const* d_in, const int* in_sizes, int n_in,
                              void* d_out, int out_size, void* d_ws, size_t ws_size,
                              hipStream_t stream) {
  (void)in_sizes; (void)n_in; (void)out_size; (void)ws_size;
  const float* hidden = (const float*)d_in[0];
  const float* n1g = (const float*)d_in[1];
  const float* n1b = (const float*)d_in[2];
  const float* qkv_w = (const float*)d_in[3];
  const float* qkv_b = (const float*)d_in[4];
  const float* proj_w = (const float*)d_in[5];
  const float* proj_b = (const float*)d_in[6];
  const float* ls1 = (const float*)d_in[7];
  const float* n2g = (const float*)d_in[8];
  const float* n2b = (const float*)d_in[9];
  const float* fc1_w = (const float*)d_in[10];
  const float* fc1_b = (const float*)d_in[11];
  const float* fc2_w = (const float*)d_in[12];
  const float* fc2_b = (const float*)d_in[13];
  const float* ls2 = (const float*)d_in[14];
  float* out = (float*)d_out;

  // workspace layout (bytes):
  //  R1:     16512*1024*2 = 33,816,576      (xnorm -> attn_out -> ynorm, padded rows)
  //  SHARED: 135,266,304   {qk 67,633,152 + vt 37,748,736}  OR  gelu 16512*4096*2
  //  W:      bf16 weights 25,165,824 (qkv|proj|fc1|fc2 contiguous)
  char* ws = (char*)d_ws;
  bf16_t* R1 = (bf16_t*)ws;
  char* shared = ws + 33816576L;
  bf16_t* qkbuf = (bf16_t*)shared;                  // [16512, 2048]
  bf16_t* vtbuf = (bf16_t*)(shared + 67633152L);    // [256, 64, SP]
  bf16_t* gelu = (bf16_t*)shared;                   // [16512, 4096]
  bf16_t* wqkv = (bf16_t*)(ws + 33816576L + 135266304L);
  bf16_t* wproj = wqkv + 3145728;
  bf16_t* wfc1 = wproj + 1048576;
  bf16_t* wfc2 = wfc1 + 4194304;

  cvt_kernel<<<12288, 256, 0, stream>>>(qkv_w, proj_w, fc1_w, fc2_w, wqkv);

  // LN1: hidden -> R1 (bf16, padded rows)
  ln_kernel<<<dim3(S_LEN, 16), 256, 0, stream>>>(hidden, n1g, n1b, R1);

  // QKV: Q (pre-scaled by SCL), K -> qkbuf [M_P,2048]; V -> vtbuf transposed
  gemm_bt<EPI_QKV><<<136 * 24, 256, 0, stream>>>(R1, wqkv, qkv_b, nullptr, nullptr,
                                                 qkbuf, nullptr, vtbuf, 3072, 1024, 24);

  // attention: qkbuf/vtbuf -> R1 [M_P,1024]
  attn_kernel<<<4352, 256, 0, stream>>>(qkbuf, vtbuf, R1);

  // proj + residual: out = hidden + ls1*(R1 @ wproj^T + b)
  gemm_bt<EPI_PROJ><<<136 * 8, 256, 0, stream>>>(R1, wproj, proj_b, hidden, ls1,
                                                 nullptr, out, nullptr, 1024, 1024, 8);

  // LN2: out -> R1
  ln_kernel<<<dim3(S_LEN, 16), 256, 0, stream>>>(out, n2g, n2b, R1);

  // FC1 + GELU: R1 @ wfc1^T + b -> gelu [M_P,4096]
  gemm_bt<EPI_FC1><<<136 * 32, 256, 0, stream>>>(R1, wfc1, fc1_b, nullptr, nullptr,
                                                 gelu, nullptr, nullptr, 4096, 1024, 32);

  // FC2 + residual: out += ls2*(gelu @ wfc2^T + b)
  gemm_bt<EPI_FC2><<<136 * 8, 256, 0, stream>>>(gelu, wfc2, fc2_b, out, ls2,
                                                nullptr, out, nullptr, 1024, 4096, 8);
}